// Round 1
// baseline (980.327 us; speedup 1.0000x reference)
//
#include <hip/hip_runtime.h>
#include <stdint.h>

typedef unsigned short u16;
typedef __attribute__((ext_vector_type(8))) short short8;
typedef __attribute__((ext_vector_type(4))) float f32x4;

#define NE   8
#define DIN  2048
#define DOUT 8192
#define NTOK 16384
#define BK   32
#define NKT  (DIN / BK)  // 64 K-steps

__device__ __forceinline__ u16 f2bf(float f) {
  uint32_t u = __builtin_bit_cast(uint32_t, f);
  u += 0x7FFFu + ((u >> 16) & 1u);   // RNE (inputs are finite normals)
  return (u16)(u >> 16);
}

__global__ __launch_bounds__(256) void cvt_f32_bf16(const float* __restrict__ src,
                                                    u16* __restrict__ dst, size_t n) {
  size_t i = ((size_t)blockIdx.x * 256 + threadIdx.x) * 8;
  const size_t stride = (size_t)gridDim.x * 256 * 8;
  for (; i < n; i += stride) {
    f32x4 a = *(const f32x4*)(src + i);
    f32x4 b = *(const f32x4*)(src + i + 4);
    short8 o;
    o[0] = (short)f2bf(a[0]); o[1] = (short)f2bf(a[1]);
    o[2] = (short)f2bf(a[2]); o[3] = (short)f2bf(a[3]);
    o[4] = (short)f2bf(b[0]); o[5] = (short)f2bf(b[1]);
    o[6] = (short)f2bf(b[2]); o[7] = (short)f2bf(b[3]);
    *(short8*)(dst + i) = o;
  }
}

#define GLOAD_LDS16(g, l) __builtin_amdgcn_global_load_lds( \
    (const __attribute__((address_space(1))) void*)(g),     \
    (__attribute__((address_space(3))) void*)(l), 16, 0, 0)

// C = X @ W[e]^T + bias[e].  X: (T, DIN) row-major.  W: (E, DOUT, DIN) row-major
// (i.e. B^T layout: both operands K-contiguous -> identical fragment loads).
// 128x128 tile, BK=32, 4 waves each computing a 64x64 quadrant as 4x4 of
// 16x16x32 bf16 MFMA fragments. Double-buffered LDS, global_load_lds width 16.
template <int FUSED>
__global__ __launch_bounds__(256) void moe_gemm(
    const float* __restrict__ Xf, const float* __restrict__ Wf,
    const u16* __restrict__ Xb, const u16* __restrict__ Wb,
    const int* __restrict__ counts, const float* __restrict__ bias,
    float* __restrict__ C) {
  __shared__ __align__(16) u16 lds[2][2][128 * BK];  // [buf][A/B][row*BK+k], 32 KB

  const int tid = threadIdx.x;
  const int lane = tid & 63;
  const int wid = tid >> 6;
  const int wr = wid >> 1;
  const int wc = wid & 1;

  // XCD-bijective swizzle (grid = 8192, %8 == 0): expert e == XCD index,
  // so each XCD streams exactly one expert's weight slab through its L2.
  const int id = blockIdx.x;
  const int swz = (id & 7) * ((int)gridDim.x >> 3) + (id >> 3);
  const int e = swz >> 10;        // 1024 tiles per expert (16 m-tiles x 64 n-tiles)
  const int rem = swz & 1023;
  const int tn = rem >> 4;        // 0..63
  const int tml = rem & 15;       // 0..15  (16 consecutive blocks share a B-panel)

  int off = 0;
  for (int i = 0; i < e; ++i) off += counts[i];  // uniform scalar loads
  const int row0 = off + tml * 128;
  const int col0 = tn * 128;
  const size_t wbase = (size_t)e * DOUT * DIN + (size_t)col0 * DIN;

  f32x4 acc[4][4] = {};

  auto stage = [&](int buf, int kt) {
    if (FUSED) {
      // fallback: fp32 load -> bf16 cvt -> ds_write (no d_ws needed)
#pragma unroll
      for (int s = 0; s < 2; ++s) {
        int i = s * 256 + tid;
        int r = i >> 2, c = i & 3;
        const float* sa = Xf + (size_t)(row0 + r) * DIN + kt * BK + c * 8;
        const float* sb = Wf + wbase + (size_t)r * DIN + kt * BK + c * 8;
        f32x4 a0 = *(const f32x4*)sa;
        f32x4 a1 = *(const f32x4*)(sa + 4);
        f32x4 b0 = *(const f32x4*)sb;
        f32x4 b1 = *(const f32x4*)(sb + 4);
        short8 va, vb;
#pragma unroll
        for (int j = 0; j < 4; ++j) {
          va[j] = (short)f2bf(a0[j]); va[j + 4] = (short)f2bf(a1[j]);
          vb[j] = (short)f2bf(b0[j]); vb[j + 4] = (short)f2bf(b1[j]);
        }
        *(short8*)&lds[buf][0][i * 8] = va;
        *(short8*)&lds[buf][1][i * 8] = vb;
      }
    } else {
      // fast: async global->LDS, 16B/lane, linear dest (wave-uniform base)
#pragma unroll
      for (int s = 0; s < 2; ++s) {
        int i = s * 256 + tid;
        int r = i >> 2, c = i & 3;
        const u16* sa = Xb + (size_t)(row0 + r) * DIN + kt * BK + c * 8;
        const u16* sb = Wb + wbase + (size_t)r * DIN + kt * BK + c * 8;
        GLOAD_LDS16(sa, &lds[buf][0][(s * 256 + wid * 64) * 8]);
        GLOAD_LDS16(sb, &lds[buf][1][(s * 256 + wid * 64) * 8]);
      }
    }
  };

  auto compute = [&](int buf) {
    const int kc = lane >> 4;   // k-chunk 0..3 (8 bf16 each)
    const int rr = lane & 15;   // row (A) / col (B) within 16x16 fragment
    short8 a[4], b[4];
    const u16* lA = lds[buf][0];
    const u16* lB = lds[buf][1];
#pragma unroll
    for (int m = 0; m < 4; ++m)
      a[m] = *(const short8*)(lA + (wr * 64 + m * 16 + rr) * BK + kc * 8);
#pragma unroll
    for (int n = 0; n < 4; ++n)
      b[n] = *(const short8*)(lB + (wc * 64 + n * 16 + rr) * BK + kc * 8);
#pragma unroll
    for (int m = 0; m < 4; ++m)
#pragma unroll
      for (int n = 0; n < 4; ++n)
        acc[m][n] = __builtin_amdgcn_mfma_f32_16x16x32_bf16(a[m], b[n], acc[m][n], 0, 0, 0);
  };

  stage(0, 0);
  for (int kt = 0; kt < NKT; ++kt) {
    __syncthreads();                               // drains stage(kt)
    if (kt + 1 < NKT) stage((kt + 1) & 1, kt + 1); // prefetch overlaps compute
    compute(kt & 1);
  }

  // epilogue: C/D layout col=lane&15, row=(lane>>4)*4+j  [m89]
  const int rbase = row0 + wr * 64;
  const int cbase = col0 + wc * 64;
#pragma unroll
  for (int n = 0; n < 4; ++n) {
    const int col = cbase + n * 16 + (lane & 15);
    const float bv = bias[e * DOUT + col];
#pragma unroll
    for (int m = 0; m < 4; ++m) {
      const int r0 = rbase + m * 16 + (lane >> 4) * 4;
#pragma unroll
      for (int j = 0; j < 4; ++j)
        C[(size_t)(r0 + j) * DOUT + col] = acc[m][n][j] + bv;
    }
  }
}

extern "C" void kernel_launch(void* const* d_in, const int* in_sizes, int n_in,
                              void* d_out, int out_size, void* d_ws, size_t ws_size,
                              hipStream_t stream) {
  const float* inp = (const float*)d_in[0];
  const int* counts = (const int*)d_in[1];
  const float* weight = (const float*)d_in[2];
  const float* bias = (const float*)d_in[3];
  float* out = (float*)d_out;

  const size_t nx = (size_t)NTOK * DIN;        // 33.5M elems
  const size_t nw = (size_t)NE * DOUT * DIN;   // 134.2M elems
  const size_t need = (nx + nw) * sizeof(u16); // 336 MB

  const int grid = (NTOK / 128) * (DOUT / 128); // 8192 blocks

  if (ws_size >= need) {
    u16* xb = (u16*)d_ws;
    u16* wb = xb + nx;
    cvt_f32_bf16<<<2048, 256, 0, stream>>>(inp, xb, nx);
    cvt_f32_bf16<<<2048, 256, 0, stream>>>(weight, wb, nw);
    moe_gemm<0><<<grid, 256, 0, stream>>>(nullptr, nullptr, xb, wb, counts, bias, out);
  } else {
    moe_gemm<1><<<grid, 256, 0, stream>>>(inp, weight, nullptr, nullptr, counts, bias, out);
  }
}

// Round 3
// 802.749 us; speedup vs baseline: 1.2212x; 1.2212x over previous
//
#include <hip/hip_runtime.h>
#include <stdint.h>

typedef unsigned short u16;
typedef __attribute__((ext_vector_type(8))) short short8;
typedef __attribute__((ext_vector_type(4))) float f32x4;

#define NE   8
#define DIN  2048
#define DOUT 8192
#define NTOK 16384

__device__ __forceinline__ u16 f2bf(float f) {
  uint32_t u = __builtin_bit_cast(uint32_t, f);
  u += 0x7FFFu + ((u >> 16) & 1u);   // RNE (inputs are finite normals)
  return (u16)(u >> 16);
}

__global__ __launch_bounds__(256) void cvt_f32_bf16(const float* __restrict__ src,
                                                    u16* __restrict__ dst, size_t n) {
  size_t i = ((size_t)blockIdx.x * 256 + threadIdx.x) * 8;
  const size_t stride = (size_t)gridDim.x * 256 * 8;
  for (; i < n; i += stride) {
    f32x4 a = *(const f32x4*)(src + i);
    f32x4 b = *(const f32x4*)(src + i + 4);
    short8 o;
    o[0] = (short)f2bf(a[0]); o[1] = (short)f2bf(a[1]);
    o[2] = (short)f2bf(a[2]); o[3] = (short)f2bf(a[3]);
    o[4] = (short)f2bf(b[0]); o[5] = (short)f2bf(b[1]);
    o[6] = (short)f2bf(b[2]); o[7] = (short)f2bf(b[3]);
    *(short8*)(dst + i) = o;
  }
}

#define GLOAD_LDS16(g, l) __builtin_amdgcn_global_load_lds( \
    (const __attribute__((address_space(1))) void*)(g),     \
    (__attribute__((address_space(3))) void*)(l), 16, 0, 0)

// ---------------------------------------------------------------------------
// 8-phase 256x256 tile, BK=64, 8 waves (2M x 4N), per-wave 128x64 output.
// LDS: [buf][A/B][kh][256 rows][32 k] bf16, 128 KiB total, double buffered.
// K-half split: each phase consumes one K-half => counted vmcnt(4) in the
// main loop; vmcnt(0) only in the FINAL tile's ph2 (r2 fix: with no new
// stages in flight, vmcnt(4) was a no-op and ph3 raced the kh1 loads).
// Swizzle: 16B-granule g ^= (row>>1)&3 (read side + pre-swizzled global src,
// linear global_load_lds dest). 2 lanes/bank-group => conflict-free.
// ---------------------------------------------------------------------------
__global__ __launch_bounds__(512, 2) void moe_gemm8(
    const u16* __restrict__ Xb, const u16* __restrict__ Wb,
    const int* __restrict__ counts, const float* __restrict__ bias,
    float* __restrict__ C) {
  extern __shared__ u16 sm[];  // 65536 u16: [buf]*32768 + [B]*16384 + [kh]*8192

  const int tid = threadIdx.x;
  const int l = tid & 63;
  const int wid = tid >> 6;      // 0..7
  const int wr = wid >> 2;       // 0..1
  const int wc = wid & 3;        // 0..3

  // XCD-bijective swizzle: 2048 blocks, 256/XCD == tiles/expert => expert==XCD
  const int id = blockIdx.x;
  const int swz = (id & 7) * 256 + (id >> 3);
  const int e = swz >> 8;
  const int rem = swz & 255;
  const int tn = rem >> 3;       // 0..31 (8 consecutive blocks share B-panel)
  const int tm = rem & 7;        // 0..7

  int off = 0;
  for (int i = 0; i < e; ++i) off += counts[i];
  const int row0 = off + tm * 256;
  const int col0 = tn * 256;
  const size_t wbase = (size_t)e * DOUT * DIN + (size_t)col0 * DIN;

  // -- staging per-lane constants (pre-swizzled global source, linear dest)
  const int rl = l >> 2;                     // row within 16-row slice
  const int q = (l & 3) ^ ((l >> 3) & 3);    // source k-granule (inverse swz)
  const int s0 = wid * 2, s1 = s0 + 1;       // this wave's 2 slices of 16
  const u16* pA0 = Xb + (size_t)(row0 + s0 * 16 + rl) * DIN + q * 8;
  const u16* pA1 = Xb + (size_t)(row0 + s1 * 16 + rl) * DIN + q * 8;
  const u16* pB0 = Wb + wbase + (size_t)(s0 * 16 + rl) * DIN + q * 8;
  const u16* pB1 = Wb + wbase + (size_t)(s1 * 16 + rl) * DIN + q * 8;

  // -- fragment-read per-lane constants (swizzled)
  const int f0 = ((l & 15) >> 1) & 3;
  const int gph = (l >> 4) ^ f0;             // physical granule 0..3
  const int aoff = (wr * 128 + (l & 15)) * 32 + gph * 8;
  const int boff = (wc * 64 + (l & 15)) * 32 + gph * 8;

  f32x4 acc[8][4] = {};
  short8 a[8], b0, b1;

#define SMA(buf, kh) (sm + (buf) * 32768 + (kh) * 8192)
#define SMB(buf, kh) (sm + (buf) * 32768 + 16384 + (kh) * 8192)
#define STAGE_A(buf, kt, kh) do { const int ko = (kt) * 64 + (kh) * 32; \
    GLOAD_LDS16(pA0 + ko, SMA(buf, kh) + s0 * 512);                     \
    GLOAD_LDS16(pA1 + ko, SMA(buf, kh) + s1 * 512); } while (0)
#define STAGE_B(buf, kt, kh) do { const int ko = (kt) * 64 + (kh) * 32; \
    GLOAD_LDS16(pB0 + ko, SMB(buf, kh) + s0 * 512);                     \
    GLOAD_LDS16(pB1 + ko, SMB(buf, kh) + s1 * 512); } while (0)
#define LDA(buf, kh) do { _Pragma("unroll") for (int m = 0; m < 8; ++m) \
    a[m] = *(const short8*)(SMA(buf, kh) + aoff + m * 512); } while (0)
#define LDB(buf, kh, n0) do {                                  \
    b0 = *(const short8*)(SMB(buf, kh) + boff + (n0) * 512);   \
    b1 = *(const short8*)(SMB(buf, kh) + boff + ((n0) + 1) * 512); } while (0)
#define FENCE() asm volatile("" ::: "memory")
#define BAR() do { FENCE(); __builtin_amdgcn_s_barrier(); FENCE(); } while (0)
#define VMW4() asm volatile("s_waitcnt vmcnt(4)" ::: "memory")
#define VMW0() asm volatile("s_waitcnt vmcnt(0)" ::: "memory")
#define MM(n0) do { __builtin_amdgcn_s_setprio(1); _Pragma("unroll")            \
    for (int m = 0; m < 8; ++m) {                                               \
      acc[m][n0] = __builtin_amdgcn_mfma_f32_16x16x32_bf16(a[m], b0, acc[m][n0], 0, 0, 0);             \
      acc[m][(n0) + 1] = __builtin_amdgcn_mfma_f32_16x16x32_bf16(a[m], b1, acc[m][(n0) + 1], 0, 0, 0); \
    }                                                                           \
    __builtin_amdgcn_s_setprio(0); } while (0)

  const int NKT = DIN / 64;  // 32 K-tiles

  // prologue: tile 0 staged in consumption order A0,B0,A1,B1
  STAGE_A(0, 0, 0); STAGE_B(0, 0, 0); STAGE_A(0, 0, 1); STAGE_B(0, 0, 1);
  VMW4();  // kh0 halves landed; kh1 (4 loads) still in flight
  BAR();

  for (int kt = 0; kt < NKT; kt += 2) {
#define TILE(cur, nxt, t) do {                                  \
    const bool hn = (t) + 1 < NKT;                              \
    /* ph1: kh0, n={0,1} */                                     \
    LDA(cur, 0); LDB(cur, 0, 0);                                \
    if (hn) STAGE_A(nxt, (t) + 1, 0);                           \
    BAR(); MM(0); BAR();                                        \
    /* ph2: kh0, n={2,3} */                                     \
    LDB(cur, 0, 2);                                             \
    /* drain this tile's kh1 halves before ph3 reads:           \
       steady state 8 in flight -> vmcnt(4); final tile has     \
       only its own 4 kh1 loads in flight -> must use vmcnt(0) */\
    if (hn) { STAGE_B(nxt, (t) + 1, 0); VMW4(); } else { VMW0(); } \
    BAR(); MM(2); BAR();                                        \
    /* ph3: kh1, n={0,1} */                                     \
    LDA(cur, 1); LDB(cur, 1, 0);                                \
    if (hn) STAGE_A(nxt, (t) + 1, 1);                           \
    BAR(); MM(0); BAR();                                        \
    /* ph4: kh1, n={2,3} */                                     \
    LDB(cur, 1, 2);                                             \
    if (hn) { STAGE_B(nxt, (t) + 1, 1); VMW4(); }               \
    BAR(); MM(2); BAR(); } while (0)
    TILE(0, 1, kt);
    TILE(1, 0, kt + 1);
#undef TILE
  }

  // epilogue: C/D layout col=lane&15, row=(lane>>4)*4+j  [m89]
  const int rb = row0 + wr * 128 + ((l >> 4) << 2);
  const int cb = col0 + wc * 64 + (l & 15);
#pragma unroll
  for (int n = 0; n < 4; ++n) {
    const int col = cb + n * 16;
    const float bv = bias[e * DOUT + col];
#pragma unroll
    for (int m = 0; m < 8; ++m) {
      const int r = rb + m * 16;
#pragma unroll
      for (int j = 0; j < 4; ++j)
        C[(size_t)(r + j) * DOUT + col] = acc[m][n][j] + bv;
    }
  }
}

// ---------------------------------------------------------------------------
// Fallback (ws too small): fused fp32->bf16 staging, 128x128 m97 structure.
// ---------------------------------------------------------------------------
__global__ __launch_bounds__(256) void moe_gemm_fused(
    const float* __restrict__ Xf, const float* __restrict__ Wf,
    const int* __restrict__ counts, const float* __restrict__ bias,
    float* __restrict__ C) {
  __shared__ __align__(16) u16 lds[2][2][128 * 32];

  const int tid = threadIdx.x;
  const int lane = tid & 63;
  const int wid = tid >> 6;
  const int wr = wid >> 1;
  const int wc = wid & 1;

  const int id = blockIdx.x;
  const int swz = (id & 7) * ((int)gridDim.x >> 3) + (id >> 3);
  const int e = swz >> 10;
  const int rem = swz & 1023;
  const int tn = rem >> 4;
  const int tml = rem & 15;

  int off = 0;
  for (int i = 0; i < e; ++i) off += counts[i];
  const int row0 = off + tml * 128;
  const int col0 = tn * 128;
  const size_t wbase = (size_t)e * DOUT * DIN + (size_t)col0 * DIN;

  f32x4 acc[4][4] = {};

  auto stage = [&](int buf, int kt) {
#pragma unroll
    for (int s = 0; s < 2; ++s) {
      int i = s * 256 + tid;
      int r = i >> 2, c = i & 3;
      const float* sa = Xf + (size_t)(row0 + r) * DIN + kt * 32 + c * 8;
      const float* sb = Wf + wbase + (size_t)r * DIN + kt * 32 + c * 8;
      f32x4 a0 = *(const f32x4*)sa;
      f32x4 a1 = *(const f32x4*)(sa + 4);
      f32x4 b0 = *(const f32x4*)sb;
      f32x4 b1 = *(const f32x4*)(sb + 4);
      short8 va, vb;
#pragma unroll
      for (int j = 0; j < 4; ++j) {
        va[j] = (short)f2bf(a0[j]); va[j + 4] = (short)f2bf(a1[j]);
        vb[j] = (short)f2bf(b0[j]); vb[j + 4] = (short)f2bf(b1[j]);
      }
      *(short8*)&lds[buf][0][i * 8] = va;
      *(short8*)&lds[buf][1][i * 8] = vb;
    }
  };

  auto compute = [&](int buf) {
    const int kc = lane >> 4;
    const int rr = lane & 15;
    short8 a[4], b[4];
    const u16* lA = lds[buf][0];
    const u16* lB = lds[buf][1];
#pragma unroll
    for (int m = 0; m < 4; ++m)
      a[m] = *(const short8*)(lA + (wr * 64 + m * 16 + rr) * 32 + kc * 8);
#pragma unroll
    for (int n = 0; n < 4; ++n)
      b[n] = *(const short8*)(lB + (wc * 64 + n * 16 + rr) * 32 + kc * 8);
#pragma unroll
    for (int m = 0; m < 4; ++m)
#pragma unroll
      for (int n = 0; n < 4; ++n)
        acc[m][n] = __builtin_amdgcn_mfma_f32_16x16x32_bf16(a[m], b[n], acc[m][n], 0, 0, 0);
  };

  stage(0, 0);
  for (int kt = 0; kt < DIN / 32; ++kt) {
    __syncthreads();
    if (kt + 1 < DIN / 32) stage((kt + 1) & 1, kt + 1);
    compute(kt & 1);
  }

  const int rbase = row0 + wr * 64;
  const int cbase = col0 + wc * 64;
#pragma unroll
  for (int n = 0; n < 4; ++n) {
    const int col = cbase + n * 16 + (lane & 15);
    const float bv = bias[e * DOUT + col];
#pragma unroll
    for (int m = 0; m < 4; ++m) {
      const int r0 = rbase + m * 16 + (lane >> 4) * 4;
#pragma unroll
      for (int j = 0; j < 4; ++j)
        C[(size_t)(r0 + j) * DOUT + col] = acc[m][n][j] + bv;
    }
  }
}

extern "C" void kernel_launch(void* const* d_in, const int* in_sizes, int n_in,
                              void* d_out, int out_size, void* d_ws, size_t ws_size,
                              hipStream_t stream) {
  const float* inp = (const float*)d_in[0];
  const int* counts = (const int*)d_in[1];
  const float* weight = (const float*)d_in[2];
  const float* bias = (const float*)d_in[3];
  float* out = (float*)d_out;

  const size_t nx = (size_t)NTOK * DIN;
  const size_t nw = (size_t)NE * DOUT * DIN;
  const size_t need = (nx + nw) * sizeof(u16);

  if (ws_size >= need) {
    u16* xb = (u16*)d_ws;
    u16* wb = xb + nx;
    cvt_f32_bf16<<<2048, 256, 0, stream>>>(inp, xb, nx);
    cvt_f32_bf16<<<2048, 256, 0, stream>>>(weight, wb, nw);
    const int grid = (NTOK / 256) * (DOUT / 256);  // 2048
    moe_gemm8<<<grid, 512, 131072, stream>>>(xb, wb, counts, bias, out);
  } else {
    const int grid = (NTOK / 128) * (DOUT / 128);  // 8192
    moe_gemm_fused<<<grid, 256, 0, stream>>>(inp, weight, counts, bias, out);
  }
}